// Round 6
// baseline (115.382 us; speedup 1.0000x reference)
//
#include <hip/hip_runtime.h>
#include <hip/hip_fp16.h>

using half8  = __attribute__((ext_vector_type(8))) _Float16;
using f32x4  = __attribute__((ext_vector_type(4))) float;

#define GROUPS      3333
#define BINNER_OUT  9999
#define BATCH       256
#define ROWS        512          // 2 spectra x 256
#define PEAKS       512
#define K1          9999
#define K1P         10048        // padded to mult of 64 (157*64)
#define NP          1024         // hidden 1000 padded
#define NOP         512          // out 500 padded

// ---- async global->LDS, 16B per lane (dest = uniform base + lane*16) ------
__device__ __forceinline__ void gl_lds16(const void* g, void* l) {
  __builtin_amdgcn_global_load_lds(
      (const __attribute__((address_space(1))) void*)g,
      (__attribute__((address_space(3))) void*)l, 16, 0, 0);
}

// ---- fused binning: per-row LDS accumulator -> h16 row --------------------
__global__ __launch_bounds__(256) void fused_bin(
    const float* __restrict__ mz1, const float* __restrict__ it1,
    const float* __restrict__ mz2, const float* __restrict__ it2,
    const float* __restrict__ Wg,  const float* __restrict__ bg,
    _Float16* __restrict__ h16) {
  __shared__ float hs[K1P];                 // 40192 B
  const int t = threadIdx.x;
  const int row = blockIdx.x;               // 0..511
  const int s = row >> 8, b = row & 255;

  for (int k = t * 4; k < K1P; k += 1024)
    *(f32x4*)&hs[k] = (f32x4){0.f, 0.f, 0.f, 0.f};
  __syncthreads();

  const float* mz = (s ? mz2 : mz1) + (size_t)b * PEAKS;
  const float* it = (s ? it2 : it1) + (size_t)b * PEAKS;
#pragma unroll
  for (int p = t; p < PEAKS; p += 256) {
    float m = mz[p], in = it[p];
    if (m >= 0.0f && m < 1000.0f) {
      int bin = (int)floorf(m / 0.01f);     // IEEE fp32 div+floor, matches jnp
      bin = bin < 0 ? 0 : (bin > 99999 ? 99999 : bin);
      if (bin < GROUPS * 30) {              // bins 99990..99999 dropped by ref
        int g = bin / 30;
        const float* w = Wg + (size_t)bin * 3;   // Wg[g][i][o] flat
        atomicAdd(&hs[g * 3 + 0], in * w[0]);
        atomicAdd(&hs[g * 3 + 1], in * w[1]);
        atomicAdd(&hs[g * 3 + 2], in * w[2]);
      }
    }
  }
  __syncthreads();

  _Float16* dst = h16 + (size_t)row * K1P;
  for (int k0 = t * 8; k0 < K1P; k0 += 2048) {
    half8 v;
#pragma unroll
    for (int j = 0; j < 8; ++j) {
      int k = k0 + j;
      float x = hs[k] + (k < BINNER_OUT ? bg[k] : 0.f);
      v[j] = (_Float16)x;
    }
    *(half8*)(dst + k0) = v;
  }
}

// ---- all weight transposes, 64x64 f32 tiles, high occupancy ---------------
// out[n*Kpad + k] = fp16(W[k*N + n]), zero-padded. Block ranges:
//   [0,2512)    W1: 157 k-tiles x 16 n-tiles
//   [2512,2768) W2: 16 x 16
//   [2768,3024) W3: 16 x 16
//   [3024,3152) Wo: 16 x 8
__global__ __launch_bounds__(256) void transp64(
    const float* __restrict__ W1, _Float16* __restrict__ W1t,
    const float* __restrict__ W2, _Float16* __restrict__ W2t,
    const float* __restrict__ W3, _Float16* __restrict__ W3t,
    const float* __restrict__ Wo, _Float16* __restrict__ Wot) {
  __shared__ float tile[64][65];            // 16640 B, <=2-way banks both ways
  int bid = blockIdx.x;
  const float* W; _Float16* outp; int K, N, Kpad, ik, in;
  if (bid < 2512)      { W = W1; outp = W1t; K = K1;   N = 1000; Kpad = K1P;
                         ik = bid % 157; in = bid / 157; }
  else if (bid < 2768) { bid -= 2512; W = W2; outp = W2t; K = 1000; N = 1000;
                         Kpad = NP; ik = bid & 15; in = bid >> 4; }
  else if (bid < 3024) { bid -= 2768; W = W3; outp = W3t; K = 1000; N = 1000;
                         Kpad = NP; ik = bid & 15; in = bid >> 4; }
  else                 { bid -= 3024; W = Wo; outp = Wot; K = 1000; N = 500;
                         Kpad = NP; ik = bid & 15; in = bid >> 4; }
  const int t = threadIdx.x;
  const int k0 = ik * 64, n0 = in * 64;
  const int r = t >> 2, cc = (t & 3) * 16;  // load: row r, cols cc..cc+15

  const int k = k0 + r;
#pragma unroll
  for (int j = 0; j < 4; ++j) {
    int n = n0 + cc + j * 4;
    f32x4 v = (f32x4){0.f, 0.f, 0.f, 0.f};
    if (k < K && n < N)                     // N % 4 == 0: whole-chunk validity
      v = *(const f32x4*)(W + (size_t)k * N + n);
    tile[r][cc + j * 4 + 0] = v[0];
    tile[r][cc + j * 4 + 1] = v[1];
    tile[r][cc + j * 4 + 2] = v[2];
    tile[r][cc + j * 4 + 3] = v[3];
  }
  __syncthreads();

  // store: row n0+r of output, k-chunk cc..cc+15 (two half8)
#pragma unroll
  for (int h = 0; h < 2; ++h) {
    half8 v;
#pragma unroll
    for (int e = 0; e < 8; ++e) v[e] = (_Float16)tile[cc + h * 8 + e][r];
    *(half8*)(outp + (size_t)(n0 + r) * Kpad + k0 + cc + h * 8) = v;
  }
}

// ---- split-K fp16 MFMA GEMM, 3-deep counted-vmcnt pipeline ----------------
// part[z] = A[M,K] * Bt[N,K]^T. Tile 64x128, BK=64, 4 waves of 32x64.
// global_load_lds(16B) staging into 3 LDS buffers; raw s_barrier + literal
// s_waitcnt vmcnt(N) keep 2 K-steps of loads in flight (never drain to 0).
// LDS rows are 128B; k-chunks XOR-swizzled (pre-swizzled global source,
// matching XOR on ds_read) -> 2 lanes/bank (free) instead of 16-way.
template <bool SWZ>
__global__ __launch_bounds__(256) void gemm_sk(
    const _Float16* __restrict__ A, int lda,
    const _Float16* __restrict__ Bt, int ldb,
    float* __restrict__ part, int M, int Npad, int ksteps_total, int kspc) {
  __shared__ __align__(16) _Float16 As[3 * 4096];   // 3 x 64x64  = 24 KB
  __shared__ __align__(16) _Float16 Bs[3 * 8192];   // 3 x 128x64 = 48 KB

  int bx, by, bz;
  if (SWZ) {   // 512 blocks = 8x8x8; each XCD owns a 2(bx) x 4(by) region
    int bid = blockIdx.x;
    int xcd = bid & 7, i = bid >> 3;
    bz = i >> 3;
    int j = i & 7;
    bx = (xcd & 3) * 2 + (j & 1);
    by = (xcd >> 2) * 4 + (j >> 1);
  } else {
    bx = blockIdx.x; by = blockIdx.y; bz = blockIdx.z;
  }

  const int t = threadIdx.x, lane = t & 63, wid = t >> 6;
  const int m0 = by * 64, n0 = bx * 128;
  const int s0 = bz * kspc;
  const int s1 = min(s0 + kspc, ksteps_total);

  const int wr = wid >> 1, wc = wid & 1;            // 2x2 waves, 32x64 each
  const int r16 = lane & 15, kh = lane >> 4;

  // staging: lane l covers row base+(l>>3), global k-chunk ((l&7)^(l>>3))*8
  const int lr  = lane >> 3;
  const int lkc = ((lane & 7) ^ lr) * 8;
  const _Float16* AgL = A  + (size_t)(m0 + wid * 16 + lr) * lda + lkc;
  const _Float16* BgL = Bt + (size_t)(n0 + wid * 32 + lr) * ldb + lkc;

  f32x4 acc[2][4] = {};

  auto STAGE = [&](int s, int buf) {
    const size_t ko = (size_t)s * 64;
    _Float16* ab = As + buf * 4096 + wid * 1024;
    _Float16* bb = Bs + buf * 8192 + wid * 2048;
    gl_lds16(AgL + ko,                     ab);
    gl_lds16(AgL + ko + (size_t) 8 * lda,  ab + 512);
    gl_lds16(BgL + ko,                     bb);
    gl_lds16(BgL + ko + (size_t) 8 * ldb,  bb + 512);
    gl_lds16(BgL + ko + (size_t)16 * ldb,  bb + 1024);
    gl_lds16(BgL + ko + (size_t)24 * ldb,  bb + 1536);
  };

  if (s0 < s1)     STAGE(s0, 0);
  if (s0 + 1 < s1) STAGE(s0 + 1, 1);

  int cur = 0;
  for (int s = s0; s < s1; ++s) {
    __builtin_amdgcn_s_barrier();           // prev step's readers are done
    const bool more2 = (s + 2 < s1), more1 = (s + 1 < s1);
    if (more2) STAGE(s + 2, cur == 0 ? 2 : (cur == 1 ? 0 : 1));
    if (more2)      asm volatile("s_waitcnt vmcnt(12)" ::: "memory");
    else if (more1) asm volatile("s_waitcnt vmcnt(6)"  ::: "memory");
    else            asm volatile("s_waitcnt vmcnt(0)"  ::: "memory");
    __builtin_amdgcn_s_barrier();           // ALL waves' stage(s) complete

    const char* Ab = (const char*)(As + cur * 4096);
    const char* Bb = (const char*)(Bs + cur * 8192);
    half8 af[2][2], bf[4][2];
#pragma unroll
    for (int kc = 0; kc < 2; ++kc) {
#pragma unroll
      for (int mi = 0; mi < 2; ++mi) {
        int row = wr * 32 + mi * 16 + r16;
        af[mi][kc] = *(const half8*)(Ab + row * 128 +
                     (((kc << 6) + (kh << 4)) ^ ((row & 7) << 4)));
      }
#pragma unroll
      for (int ni = 0; ni < 4; ++ni) {
        int row = wc * 64 + ni * 16 + r16;
        bf[ni][kc] = *(const half8*)(Bb + row * 128 +
                     (((kc << 6) + (kh << 4)) ^ ((row & 7) << 4)));
      }
    }
#pragma unroll
    for (int kc = 0; kc < 2; ++kc)
#pragma unroll
      for (int mi = 0; mi < 2; ++mi)
#pragma unroll
        for (int ni = 0; ni < 4; ++ni)
          acc[mi][ni] = __builtin_amdgcn_mfma_f32_16x16x32_f16(
              af[mi][kc], bf[ni][kc], acc[mi][ni], 0, 0, 0);
    cur = cur == 2 ? 0 : cur + 1;
  }

  float* P = part + (size_t)bz * M * Npad;
#pragma unroll
  for (int mi = 0; mi < 2; ++mi)
#pragma unroll
    for (int ni = 0; ni < 4; ++ni) {
      int row = m0 + wr * 32 + mi * 16 + kh * 4;    // C/D: row=(l>>4)*4+rr
      int col = n0 + wc * 64 + ni * 16 + r16;       //      col=l&15
#pragma unroll
      for (int rr = 0; rr < 4; ++rr)
        P[(size_t)(row + rr) * Npad + col] = acc[mi][ni][rr];
    }
}

// ---- combine split-K partials + bias + relu, emit fp16 --------------------
__global__ void combine_sk(const float* __restrict__ part, int SK, int M, int Npad,
                           const float* __restrict__ bias, int Nreal,
                           _Float16* __restrict__ o16) {
  int idx = blockIdx.x * 256 + threadIdx.x;
  int total = M * Npad;
  if (idx >= total) return;
  int n = idx & (Npad - 1);  // Npad is a power of two
  float s = 0.f;
  for (int zz = 0; zz < SK; ++zz) s += part[(size_t)zz * total + idx];
  s += (n < Nreal) ? bias[n] : 0.f;
  o16[idx] = (_Float16)fmaxf(s, 0.f);
}

// ---- final combine (split-K + bias, no relu) fused with cosine ------------
__global__ void combine_cos(const float* __restrict__ part,
                            const float* __restrict__ bo,
                            float* __restrict__ out) {
  const int b = blockIdx.x, t = threadIdx.x;
  float d = 0.f, s1 = 0.f, s2 = 0.f;
  for (int c = t; c < NOP; c += 256) {
    float e1 = 0.f, e2 = 0.f;
#pragma unroll
    for (int z = 0; z < 8; ++z) {
      e1 += part[((size_t)z * ROWS + b) * NOP + c];
      e2 += part[((size_t)z * ROWS + b + BATCH) * NOP + c];
    }
    if (c < 500) { float bb = bo[c]; e1 += bb; e2 += bb; }
    d += e1 * e2; s1 += e1 * e1; s2 += e2 * e2;
  }
  for (int off = 32; off > 0; off >>= 1) {
    d  += __shfl_down(d, off, 64);
    s1 += __shfl_down(s1, off, 64);
    s2 += __shfl_down(s2, off, 64);
  }
  __shared__ float rd[4], r1[4], r2[4];
  int wd = t >> 6, lane = t & 63;
  if (lane == 0) { rd[wd] = d; r1[wd] = s1; r2[wd] = s2; }
  __syncthreads();
  if (t == 0) {
    float D  = rd[0] + rd[1] + rd[2] + rd[3];
    float S1 = r1[0] + r1[1] + r1[2] + r1[3];
    float S2 = r2[0] + r2[1] + r2[2] + r2[3];
    float n1 = fmaxf(sqrtf(S1), 1e-6f);
    float n2 = fmaxf(sqrtf(S2), 1e-6f);
    out[b] = D / (n1 * n2);
  }
}

extern "C" void kernel_launch(void* const* d_in, const int* in_sizes, int n_in,
                              void* d_out, int out_size, void* d_ws, size_t ws_size,
                              hipStream_t stream) {
  const float* mz1 = (const float*)d_in[0];
  const float* it1 = (const float*)d_in[1];
  const float* mz2 = (const float*)d_in[2];
  const float* it2 = (const float*)d_in[3];
  const float* Wg  = (const float*)d_in[4];
  const float* bg  = (const float*)d_in[5];
  const float* W1  = (const float*)d_in[6];
  const float* b1  = (const float*)d_in[7];
  const float* W2  = (const float*)d_in[8];
  const float* b2  = (const float*)d_in[9];
  const float* W3  = (const float*)d_in[10];
  const float* b3  = (const float*)d_in[11];
  const float* Wo  = (const float*)d_in[12];
  const float* bo  = (const float*)d_in[13];
  float* out = (float*)d_out;

  char* ws = (char*)d_ws;
  size_t off = 0;
  auto take = [&](size_t bytes) {
    size_t o = off; off += (bytes + 255) & ~(size_t)255; return o;
  };
  float*    part = (float*)   (ws + take((size_t)8 * ROWS * NP * 4));  // 16MB
  _Float16* h16  = (_Float16*)(ws + take((size_t)ROWS * K1P * 2));
  _Float16* W1t  = (_Float16*)(ws + take((size_t)NP * K1P * 2));
  _Float16* W2t  = (_Float16*)(ws + take((size_t)NP * NP * 2));
  _Float16* W3t  = (_Float16*)(ws + take((size_t)NP * NP * 2));
  _Float16* Wot  = (_Float16*)(ws + take((size_t)NOP * NP * 2));
  _Float16* y1   = (_Float16*)(ws + take((size_t)ROWS * NP * 2));
  _Float16* y2   = (_Float16*)(ws + take((size_t)ROWS * NP * 2));
  _Float16* y3   = (_Float16*)(ws + take((size_t)ROWS * NP * 2));

  // 1) binning + grouped linear (512 blocks); weight transposes (3152 blocks)
  fused_bin<<<ROWS, 256, 0, stream>>>(mz1, it1, mz2, it2, Wg, bg, h16);
  transp64<<<3152, 256, 0, stream>>>(W1, W1t, W2, W2t, W3, W3t, Wo, Wot);

  // 2) MLP. L1: 157 K-steps of 64, SK=8 (kspc 20); L2/L3/Lo: 16 steps, SK=8.
  gemm_sk<true><<<512, 256, 0, stream>>>(
      h16, K1P, W1t, K1P, part, ROWS, NP, K1P / 64, 20);
  combine_sk<<<(ROWS * NP) / 256, 256, 0, stream>>>(part, 8, ROWS, NP, b1, 1000, y1);

  gemm_sk<true><<<512, 256, 0, stream>>>(
      y1, NP, W2t, NP, part, ROWS, NP, NP / 64, 2);
  combine_sk<<<(ROWS * NP) / 256, 256, 0, stream>>>(part, 8, ROWS, NP, b2, 1000, y2);

  gemm_sk<true><<<512, 256, 0, stream>>>(
      y2, NP, W3t, NP, part, ROWS, NP, NP / 64, 2);
  combine_sk<<<(ROWS * NP) / 256, 256, 0, stream>>>(part, 8, ROWS, NP, b3, 1000, y3);

  gemm_sk<false><<<dim3(NOP / 128, ROWS / 64, 8), 256, 0, stream>>>(
      y3, NP, Wot, NP, part, ROWS, NOP, NP / 64, 2);

  // 3) final combine + cosine
  combine_cos<<<BATCH, 256, 0, stream>>>(part, bo, out);
}

// Round 7
// 101.265 us; speedup vs baseline: 1.1394x; 1.1394x over previous
//
#include <hip/hip_runtime.h>
#include <hip/hip_fp16.h>

using half8  = __attribute__((ext_vector_type(8))) _Float16;
using f32x4  = __attribute__((ext_vector_type(4))) float;

#define GROUPS      3333
#define BINNER_OUT  9999
#define BATCH       256
#define ROWS        512          // 2 spectra x 256
#define PEAKS       512
#define K1          9999
#define K1P         10048        // padded to mult of 64 (157*64)
#define NP          1024         // hidden 1000 padded
#define NOP         512          // out 500 padded
#define HALFK       5024         // K1P/2, per-bin-block column range

// ---- async global->LDS, 16B per lane (dest = uniform base + lane*16) ------
__device__ __forceinline__ void gl_lds16(const void* g, void* l) {
  __builtin_amdgcn_global_load_lds(
      (const __attribute__((address_space(1))) void*)g,
      (__attribute__((address_space(3))) void*)l, 16, 0, 0);
}

// ---- prep2: binning (1024 blocks, half-row each) + transposes (3152) ------
// Uniform 20.1 KB LDS -> 8 blocks/CU for both paths.
// bin path  [0,1024):   block bid: row=bid>>1, half=bid&1; LDS hist of
//   output cols [half*5024, half*5024+5024); per-column filter keeps each
//   column's atomic adds in exactly one block. Emit fp16(+bg), zero-pad.
// transp    [1024,4176): 64x64 f32 tile; out[n*Kpad+k] = fp16(W[k*N+n]).
//   [0,2512) W1 (157 k x 16 n), [2512,2768) W2, [2768,3024) W3, [3024,3152) Wo
__global__ __launch_bounds__(256) void prep2(
    const float* __restrict__ mz1, const float* __restrict__ it1,
    const float* __restrict__ mz2, const float* __restrict__ it2,
    const float* __restrict__ Wg,  const float* __restrict__ bg,
    _Float16* __restrict__ h16,
    const float* __restrict__ W1, _Float16* __restrict__ W1t,
    const float* __restrict__ W2, _Float16* __restrict__ W2t,
    const float* __restrict__ W3, _Float16* __restrict__ W3t,
    const float* __restrict__ Wo, _Float16* __restrict__ Wot) {
  __shared__ __align__(16) char smem[HALFK * 4];    // 20096 B
  const int t = threadIdx.x;
  const int blk = blockIdx.x;

  if (blk < 1024) {
    // ---------------- binning + grouped linear (half row) ----------------
    float* hs = (float*)smem;                       // 5024 floats
    const int row = blk >> 1, half = blk & 1;
    const int base = half * HALFK;
    const int s = row >> 8, b = row & 255;

    for (int k = t * 4; k < HALFK; k += 1024)
      *(f32x4*)&hs[k] = (f32x4){0.f, 0.f, 0.f, 0.f};
    __syncthreads();

    const float* mz = (s ? mz2 : mz1) + (size_t)b * PEAKS;
    const float* it = (s ? it2 : it1) + (size_t)b * PEAKS;
#pragma unroll
    for (int p = t; p < PEAKS; p += 256) {
      float m = mz[p], in = it[p];
      if (m >= 0.0f && m < 1000.0f) {
        int bin = (int)floorf(m / 0.01f);   // IEEE fp32 div+floor, matches jnp
        bin = bin < 0 ? 0 : (bin > 99999 ? 99999 : bin);
        if (bin < GROUPS * 30) {            // bins 99990..99999 dropped by ref
          int g = bin / 30;
          int c0 = g * 3;
          if (c0 + 2 >= base && c0 < base + HALFK) {
            const float* w = Wg + (size_t)bin * 3;
#pragma unroll
            for (int o = 0; o < 3; ++o) {
              int c = c0 + o;
              if (c >= base && c < base + HALFK)
                atomicAdd(&hs[c - base], in * w[o]);
            }
          }
        }
      }
    }
    __syncthreads();

    _Float16* dst = h16 + (size_t)row * K1P + base;
    for (int k0 = t * 8; k0 < HALFK; k0 += 2048) {
      half8 v;
#pragma unroll
      for (int j = 0; j < 8; ++j) {
        int c = base + k0 + j;
        float x = hs[k0 + j] + (c < BINNER_OUT ? bg[c] : 0.f);
        v[j] = (_Float16)x;
      }
      *(half8*)(dst + k0) = v;
    }
  } else {
    // ---------------- weight transpose+convert, 64x64 tiles ----------------
    float (*tile)[65] = (float(*)[65])smem;         // 16640 B
    int bid = blk - 1024;
    const float* W; _Float16* outp; int K, N, Kpad, ik, in;
    if (bid < 2512)      { W = W1; outp = W1t; K = K1;   N = 1000; Kpad = K1P;
                           ik = bid % 157; in = bid / 157; }
    else if (bid < 2768) { bid -= 2512; W = W2; outp = W2t; K = 1000; N = 1000;
                           Kpad = NP; ik = bid & 15; in = bid >> 4; }
    else if (bid < 3024) { bid -= 2768; W = W3; outp = W3t; K = 1000; N = 1000;
                           Kpad = NP; ik = bid & 15; in = bid >> 4; }
    else                 { bid -= 3024; W = Wo; outp = Wot; K = 1000; N = 500;
                           Kpad = NP; ik = bid & 15; in = bid >> 4; }
    const int k0 = ik * 64, n0 = in * 64;
    const int r = t >> 2, cc = (t & 3) * 16;

    const int k = k0 + r;
#pragma unroll
    for (int j = 0; j < 4; ++j) {
      int n = n0 + cc + j * 4;
      f32x4 v = (f32x4){0.f, 0.f, 0.f, 0.f};
      if (k < K && n < N)                   // N % 4 == 0: whole-chunk validity
        v = *(const f32x4*)(W + (size_t)k * N + n);
      tile[r][cc + j * 4 + 0] = v[0];
      tile[r][cc + j * 4 + 1] = v[1];
      tile[r][cc + j * 4 + 2] = v[2];
      tile[r][cc + j * 4 + 3] = v[3];
    }
    __syncthreads();

#pragma unroll
    for (int h = 0; h < 2; ++h) {
      half8 v;
#pragma unroll
      for (int e = 0; e < 8; ++e) v[e] = (_Float16)tile[cc + h * 8 + e][r];
      *(half8*)(outp + (size_t)(n0 + r) * Kpad + k0 + cc + h * 8) = v;
    }
  }
}

// ---- split-K fp16 MFMA GEMM, 3-deep counted-vmcnt pipeline ----------------
// part[z] = A[M,K] * Bt[N,K]^T. Tile 64x128, BK=64, 4 waves of 32x64.
// global_load_lds(16B) staging into 3 LDS buffers; raw s_barrier + literal
// s_waitcnt vmcnt(N) keep 2 K-steps of loads in flight (never drain to 0).
// LDS rows are 128B; k-chunks XOR-swizzled (pre-swizzled global source,
// matching XOR on ds_read) -> 2 lanes/bank (free) instead of 16-way.
template <bool SWZ>
__global__ __launch_bounds__(256) void gemm_sk(
    const _Float16* __restrict__ A, int lda,
    const _Float16* __restrict__ Bt, int ldb,
    float* __restrict__ part, int M, int Npad, int ksteps_total, int kspc) {
  __shared__ __align__(16) _Float16 As[3 * 4096];   // 3 x 64x64  = 24 KB
  __shared__ __align__(16) _Float16 Bs[3 * 8192];   // 3 x 128x64 = 48 KB

  int bx, by, bz;
  if (SWZ) {   // 512 blocks = 8x8x8; each XCD owns a 2(bx) x 4(by) region
    int bid = blockIdx.x;
    int xcd = bid & 7, i = bid >> 3;
    bz = i >> 3;
    int j = i & 7;
    bx = (xcd & 3) * 2 + (j & 1);
    by = (xcd >> 2) * 4 + (j >> 1);
  } else {
    bx = blockIdx.x; by = blockIdx.y; bz = blockIdx.z;
  }

  const int t = threadIdx.x, lane = t & 63, wid = t >> 6;
  const int m0 = by * 64, n0 = bx * 128;
  const int s0 = bz * kspc;
  const int s1 = min(s0 + kspc, ksteps_total);

  const int wr = wid >> 1, wc = wid & 1;            // 2x2 waves, 32x64 each
  const int r16 = lane & 15, kh = lane >> 4;

  // staging: lane l covers row base+(l>>3), global k-chunk ((l&7)^(l>>3))*8
  const int lr  = lane >> 3;
  const int lkc = ((lane & 7) ^ lr) * 8;
  const _Float16* AgL = A  + (size_t)(m0 + wid * 16 + lr) * lda + lkc;
  const _Float16* BgL = Bt + (size_t)(n0 + wid * 32 + lr) * ldb + lkc;

  f32x4 acc[2][4] = {};

  auto STAGE = [&](int s, int buf) {
    const size_t ko = (size_t)s * 64;
    _Float16* ab = As + buf * 4096 + wid * 1024;
    _Float16* bb = Bs + buf * 8192 + wid * 2048;
    gl_lds16(AgL + ko,                     ab);
    gl_lds16(AgL + ko + (size_t) 8 * lda,  ab + 512);
    gl_lds16(BgL + ko,                     bb);
    gl_lds16(BgL + ko + (size_t) 8 * ldb,  bb + 512);
    gl_lds16(BgL + ko + (size_t)16 * ldb,  bb + 1024);
    gl_lds16(BgL + ko + (size_t)24 * ldb,  bb + 1536);
  };

  if (s0 < s1)     STAGE(s0, 0);
  if (s0 + 1 < s1) STAGE(s0 + 1, 1);

  int cur = 0;
  for (int s = s0; s < s1; ++s) {
    __builtin_amdgcn_s_barrier();           // prev step's readers are done
    const bool more2 = (s + 2 < s1), more1 = (s + 1 < s1);
    if (more2) STAGE(s + 2, cur == 0 ? 2 : (cur == 1 ? 0 : 1));
    if (more2)      asm volatile("s_waitcnt vmcnt(12)" ::: "memory");
    else if (more1) asm volatile("s_waitcnt vmcnt(6)"  ::: "memory");
    else            asm volatile("s_waitcnt vmcnt(0)"  ::: "memory");
    __builtin_amdgcn_s_barrier();           // ALL waves' stage(s) complete

    const char* Ab = (const char*)(As + cur * 4096);
    const char* Bb = (const char*)(Bs + cur * 8192);
    half8 af[2][2], bf[4][2];
#pragma unroll
    for (int kc = 0; kc < 2; ++kc) {
#pragma unroll
      for (int mi = 0; mi < 2; ++mi) {
        int row = wr * 32 + mi * 16 + r16;
        af[mi][kc] = *(const half8*)(Ab + row * 128 +
                     (((kc << 6) + (kh << 4)) ^ ((row & 7) << 4)));
      }
#pragma unroll
      for (int ni = 0; ni < 4; ++ni) {
        int row = wc * 64 + ni * 16 + r16;
        bf[ni][kc] = *(const half8*)(Bb + row * 128 +
                     (((kc << 6) + (kh << 4)) ^ ((row & 7) << 4)));
      }
    }
#pragma unroll
    for (int kc = 0; kc < 2; ++kc)
#pragma unroll
      for (int mi = 0; mi < 2; ++mi)
#pragma unroll
        for (int ni = 0; ni < 4; ++ni)
          acc[mi][ni] = __builtin_amdgcn_mfma_f32_16x16x32_f16(
              af[mi][kc], bf[ni][kc], acc[mi][ni], 0, 0, 0);
    cur = cur == 2 ? 0 : cur + 1;
  }

  float* P = part + (size_t)bz * M * Npad;
#pragma unroll
  for (int mi = 0; mi < 2; ++mi)
#pragma unroll
    for (int ni = 0; ni < 4; ++ni) {
      int row = m0 + wr * 32 + mi * 16 + kh * 4;    // C/D: row=(l>>4)*4+rr
      int col = n0 + wc * 64 + ni * 16 + r16;       //      col=l&15
#pragma unroll
      for (int rr = 0; rr < 4; ++rr)
        P[(size_t)(row + rr) * Npad + col] = acc[mi][ni][rr];
    }
}

// ---- combine split-K partials + bias + relu, emit fp16 --------------------
__global__ void combine_sk(const float* __restrict__ part, int SK, int M, int Npad,
                           const float* __restrict__ bias, int Nreal,
                           _Float16* __restrict__ o16) {
  int idx = blockIdx.x * 256 + threadIdx.x;
  int total = M * Npad;
  if (idx >= total) return;
  int n = idx & (Npad - 1);  // Npad is a power of two
  float s = 0.f;
  for (int zz = 0; zz < SK; ++zz) s += part[(size_t)zz * total + idx];
  s += (n < Nreal) ? bias[n] : 0.f;
  o16[idx] = (_Float16)fmaxf(s, 0.f);
}

// ---- final combine (split-K + bias, no relu) fused with cosine ------------
__global__ void combine_cos(const float* __restrict__ part,
                            const float* __restrict__ bo,
                            float* __restrict__ out) {
  const int b = blockIdx.x, t = threadIdx.x;
  float d = 0.f, s1 = 0.f, s2 = 0.f;
  for (int c = t; c < NOP; c += 256) {
    float e1 = 0.f, e2 = 0.f;
#pragma unroll
    for (int z = 0; z < 8; ++z) {
      e1 += part[((size_t)z * ROWS + b) * NOP + c];
      e2 += part[((size_t)z * ROWS + b + BATCH) * NOP + c];
    }
    if (c < 500) { float bb = bo[c]; e1 += bb; e2 += bb; }
    d += e1 * e2; s1 += e1 * e1; s2 += e2 * e2;
  }
  for (int off = 32; off > 0; off >>= 1) {
    d  += __shfl_down(d, off, 64);
    s1 += __shfl_down(s1, off, 64);
    s2 += __shfl_down(s2, off, 64);
  }
  __shared__ float rd[4], r1[4], r2[4];
  int wd = t >> 6, lane = t & 63;
  if (lane == 0) { rd[wd] = d; r1[wd] = s1; r2[wd] = s2; }
  __syncthreads();
  if (t == 0) {
    float D  = rd[0] + rd[1] + rd[2] + rd[3];
    float S1 = r1[0] + r1[1] + r1[2] + r1[3];
    float S2 = r2[0] + r2[1] + r2[2] + r2[3];
    float n1 = fmaxf(sqrtf(S1), 1e-6f);
    float n2 = fmaxf(sqrtf(S2), 1e-6f);
    out[b] = D / (n1 * n2);
  }
}

extern "C" void kernel_launch(void* const* d_in, const int* in_sizes, int n_in,
                              void* d_out, int out_size, void* d_ws, size_t ws_size,
                              hipStream_t stream) {
  const float* mz1 = (const float*)d_in[0];
  const float* it1 = (const float*)d_in[1];
  const float* mz2 = (const float*)d_in[2];
  const float* it2 = (const float*)d_in[3];
  const float* Wg  = (const float*)d_in[4];
  const float* bg  = (const float*)d_in[5];
  const float* W1  = (const float*)d_in[6];
  const float* b1  = (const float*)d_in[7];
  const float* W2  = (const float*)d_in[8];
  const float* b2  = (const float*)d_in[9];
  const float* W3  = (const float*)d_in[10];
  const float* b3  = (const float*)d_in[11];
  const float* Wo  = (const float*)d_in[12];
  const float* bo  = (const float*)d_in[13];
  float* out = (float*)d_out;

  char* ws = (char*)d_ws;
  size_t off = 0;
  auto take = [&](size_t bytes) {
    size_t o = off; off += (bytes + 255) & ~(size_t)255; return o;
  };
  float*    part = (float*)   (ws + take((size_t)8 * ROWS * NP * 4));  // 16MB
  _Float16* h16  = (_Float16*)(ws + take((size_t)ROWS * K1P * 2));
  _Float16* W1t  = (_Float16*)(ws + take((size_t)NP * K1P * 2));
  _Float16* W2t  = (_Float16*)(ws + take((size_t)NP * NP * 2));
  _Float16* W3t  = (_Float16*)(ws + take((size_t)NP * NP * 2));
  _Float16* Wot  = (_Float16*)(ws + take((size_t)NOP * NP * 2));
  _Float16* y1   = (_Float16*)(ws + take((size_t)ROWS * NP * 2));
  _Float16* y2   = (_Float16*)(ws + take((size_t)ROWS * NP * 2));
  _Float16* y3   = (_Float16*)(ws + take((size_t)ROWS * NP * 2));

  // 1) binning + grouped linear + all weight transposes, ONE dispatch,
  //    uniform 20.1 KB LDS -> 8 blocks/CU everywhere
  prep2<<<4176, 256, 0, stream>>>(mz1, it1, mz2, it2, Wg, bg, h16,
                                  W1, W1t, W2, W2t, W3, W3t, Wo, Wot);

  // 2) MLP. L1: 157 K-steps of 64, SK=8 (kspc 20); L2/L3/Lo: 16 steps, SK=8.
  gemm_sk<true><<<512, 256, 0, stream>>>(
      h16, K1P, W1t, K1P, part, ROWS, NP, K1P / 64, 20);
  combine_sk<<<(ROWS * NP) / 256, 256, 0, stream>>>(part, 8, ROWS, NP, b1, 1000, y1);

  gemm_sk<true><<<512, 256, 0, stream>>>(
      y1, NP, W2t, NP, part, ROWS, NP, NP / 64, 2);
  combine_sk<<<(ROWS * NP) / 256, 256, 0, stream>>>(part, 8, ROWS, NP, b2, 1000, y2);

  gemm_sk<true><<<512, 256, 0, stream>>>(
      y2, NP, W3t, NP, part, ROWS, NP, NP / 64, 2);
  combine_sk<<<(ROWS * NP) / 256, 256, 0, stream>>>(part, 8, ROWS, NP, b3, 1000, y3);

  gemm_sk<false><<<dim3(NOP / 128, ROWS / 64, 8), 256, 0, stream>>>(
      y3, NP, Wot, NP, part, ROWS, NOP, NP / 64, 2);

  // 3) final combine + cosine
  combine_cos<<<BATCH, 256, 0, stream>>>(part, bo, out);
}

// Round 8
// 98.252 us; speedup vs baseline: 1.1743x; 1.0307x over previous
//
#include <hip/hip_runtime.h>
#include <hip/hip_fp16.h>

using half8  = __attribute__((ext_vector_type(8))) _Float16;
using half4  = __attribute__((ext_vector_type(4))) _Float16;
using f32x4  = __attribute__((ext_vector_type(4))) float;

#define GROUPS      3333
#define BINNER_OUT  9999
#define BATCH       256
#define ROWS        512          // 2 spectra x 256
#define PEAKS       512
#define K1          9999
#define K1P         10048        // padded to mult of 64 (157*64)
#define NP          1024         // hidden 1000 padded
#define NOP         512          // out 500 padded
#define HALFK       5024         // K1P/2, per-bin-block column range

// ---- async global->LDS, 16B per lane (dest = uniform base + lane*16) ------
__device__ __forceinline__ void gl_lds16(const void* g, void* l) {
  __builtin_amdgcn_global_load_lds(
      (const __attribute__((address_space(1))) void*)g,
      (__attribute__((address_space(3))) void*)l, 16, 0, 0);
}

// ---- prep3: binning (1024 blocks, half-row each) + transposes (800) -------
// Uniform 20.1 KB LDS -> 8 blocks/CU for both paths.
// bin path  [0,1024):  row=bid>>1, half=bid&1; LDS hist of output cols
//   [half*5024, +5024); per-column filter keeps atomics in one block.
// transp    [1024,1824): each block does 4 consecutive 64x64 k-tiles with
//   T14 register staging: next tile's global loads issued BEFORE the
//   current tile's LDS column-read + store phase (loads in flight across it).
__global__ __launch_bounds__(256) void prep3(
    const float* __restrict__ mz1, const float* __restrict__ it1,
    const float* __restrict__ mz2, const float* __restrict__ it2,
    const float* __restrict__ Wg,  const float* __restrict__ bg,
    _Float16* __restrict__ h16,
    const float* __restrict__ W1, _Float16* __restrict__ W1t,
    const float* __restrict__ W2, _Float16* __restrict__ W2t,
    const float* __restrict__ W3, _Float16* __restrict__ W3t,
    const float* __restrict__ Wo, _Float16* __restrict__ Wot) {
  __shared__ __align__(16) char smem[HALFK * 4];    // 20096 B
  const int t = threadIdx.x;
  const int blk = blockIdx.x;

  if (blk < 1024) {
    // ---------------- binning + grouped linear (half row) ----------------
    float* hs = (float*)smem;                       // 5024 floats
    const int row = blk >> 1, half = blk & 1;
    const int base = half * HALFK;
    const int s = row >> 8, b = row & 255;

    for (int k = t * 4; k < HALFK; k += 1024)
      *(f32x4*)&hs[k] = (f32x4){0.f, 0.f, 0.f, 0.f};
    __syncthreads();

    const float* mz = (s ? mz2 : mz1) + (size_t)b * PEAKS;
    const float* it = (s ? it2 : it1) + (size_t)b * PEAKS;
#pragma unroll
    for (int p = t; p < PEAKS; p += 256) {
      float m = mz[p], in = it[p];
      if (m >= 0.0f && m < 1000.0f) {
        int bin = (int)floorf(m / 0.01f);   // IEEE fp32 div+floor, matches jnp
        bin = bin < 0 ? 0 : (bin > 99999 ? 99999 : bin);
        if (bin < GROUPS * 30) {            // bins 99990..99999 dropped by ref
          int g = bin / 30;
          int c0 = g * 3;
          if (c0 + 2 >= base && c0 < base + HALFK) {
            const float* w = Wg + (size_t)bin * 3;
#pragma unroll
            for (int o = 0; o < 3; ++o) {
              int c = c0 + o;
              if (c >= base && c < base + HALFK)
                atomicAdd(&hs[c - base], in * w[o]);
            }
          }
        }
      }
    }
    __syncthreads();

    _Float16* dst = h16 + (size_t)row * K1P + base;
    for (int k0 = t * 8; k0 < HALFK; k0 += 2048) {
      half8 v;
#pragma unroll
      for (int j = 0; j < 8; ++j) {
        int c = base + k0 + j;
        float x = hs[k0 + j] + (c < BINNER_OUT ? bg[c] : 0.f);
        v[j] = (_Float16)x;
      }
      *(half8*)(dst + k0) = v;
    }
  } else {
    // ------- weight transpose+convert, 4 x (64x64) tiles per block -------
    // out[n*Kpad + k] = fp16(W[k*N + n]), zero-padded.
    float (*tile)[66] = (float(*)[66])smem;         // 16896 B
    int bid = blk - 1024;
    const float* W; _Float16* outp; int K, N, Kpad, g, in, ktiles;
    if (bid < 640)       { W = W1; outp = W1t; K = K1;   N = 1000; Kpad = K1P;
                           ktiles = 157; g = bid % 40; in = bid / 40; }
    else if (bid < 704)  { bid -= 640; W = W2; outp = W2t; K = 1000; N = 1000;
                           Kpad = NP; ktiles = 16; g = bid & 3; in = bid >> 2; }
    else if (bid < 768)  { bid -= 704; W = W3; outp = W3t; K = 1000; N = 1000;
                           Kpad = NP; ktiles = 16; g = bid & 3; in = bid >> 2; }
    else                 { bid -= 768; W = Wo; outp = Wot; K = 1000; N = 500;
                           Kpad = NP; ktiles = 16; g = bid & 3; in = bid >> 2; }
    const int ntile = min(4, ktiles - g * 4);
    const int k0base = g * 256, n0 = in * 64;
    const int r = t >> 2, cc = (t & 3) * 16;

    f32x4 cur[4], nxt[4];
    auto LOAD = [&](int i, f32x4* dst) {            // tile i of this group
      int k = k0base + i * 64 + r;
#pragma unroll
      for (int j = 0; j < 4; ++j) {
        int n = n0 + cc + j * 4;
        f32x4 v = (f32x4){0.f, 0.f, 0.f, 0.f};
        if (k < K && n < N)                 // N % 4 == 0: whole-chunk validity
          v = *(const f32x4*)(W + (size_t)k * N + n);
        dst[j] = v;
      }
    };

    LOAD(0, cur);
    for (int i = 0; i < ntile; ++i) {
      if (i) __syncthreads();               // prior tile's col-reads done
#pragma unroll
      for (int j = 0; j < 4; ++j) {
        tile[r][cc + j * 4 + 0] = cur[j][0];
        tile[r][cc + j * 4 + 1] = cur[j][1];
        tile[r][cc + j * 4 + 2] = cur[j][2];
        tile[r][cc + j * 4 + 3] = cur[j][3];
      }
      __syncthreads();
      if (i + 1 < ntile) LOAD(i + 1, nxt);  // in flight across store phase
      const int k0 = k0base + i * 64;
#pragma unroll
      for (int h = 0; h < 2; ++h) {
        half8 v;
#pragma unroll
        for (int e = 0; e < 8; ++e) v[e] = (_Float16)tile[cc + h * 8 + e][r];
        *(half8*)(outp + (size_t)(n0 + r) * Kpad + k0 + cc + h * 8) = v;
      }
#pragma unroll
      for (int j = 0; j < 4; ++j) cur[j] = nxt[j];
    }
  }
}

// ---- split-K fp16 MFMA GEMM, 3-deep counted-vmcnt pipeline ----------------
// part[z] = A[M,K] * Bt[N,K]^T. Tile 64x128, BK=64, 4 waves of 32x64.
// global_load_lds(16B) staging into 3 LDS buffers; raw s_barrier + literal
// s_waitcnt vmcnt(N) keep 2 K-steps of loads in flight (never drain to 0).
// LDS rows are 128B; k-chunks XOR-swizzled (pre-swizzled global source,
// matching XOR on ds_read) -> 2 lanes/bank (free) instead of 16-way.
template <bool SWZ>
__global__ __launch_bounds__(256) void gemm_sk(
    const _Float16* __restrict__ A, int lda,
    const _Float16* __restrict__ Bt, int ldb,
    float* __restrict__ part, int M, int Npad, int ksteps_total, int kspc) {
  __shared__ __align__(16) _Float16 As[3 * 4096];   // 3 x 64x64  = 24 KB
  __shared__ __align__(16) _Float16 Bs[3 * 8192];   // 3 x 128x64 = 48 KB

  int bx, by, bz;
  if (SWZ) {   // 512 blocks = 8x8x8; each XCD owns a 2(bx) x 4(by) region
    int bid = blockIdx.x;
    int xcd = bid & 7, i = bid >> 3;
    bz = i >> 3;
    int j = i & 7;
    bx = (xcd & 3) * 2 + (j & 1);
    by = (xcd >> 2) * 4 + (j >> 1);
  } else {
    bx = blockIdx.x; by = blockIdx.y; bz = blockIdx.z;
  }

  const int t = threadIdx.x, lane = t & 63, wid = t >> 6;
  const int m0 = by * 64, n0 = bx * 128;
  const int s0 = bz * kspc;
  const int s1 = min(s0 + kspc, ksteps_total);

  const int wr = wid >> 1, wc = wid & 1;            // 2x2 waves, 32x64 each
  const int r16 = lane & 15, kh = lane >> 4;

  // staging: lane l covers row base+(l>>3), global k-chunk ((l&7)^(l>>3))*8
  const int lr  = lane >> 3;
  const int lkc = ((lane & 7) ^ lr) * 8;
  const _Float16* AgL = A  + (size_t)(m0 + wid * 16 + lr) * lda + lkc;
  const _Float16* BgL = Bt + (size_t)(n0 + wid * 32 + lr) * ldb + lkc;

  f32x4 acc[2][4] = {};

  auto STAGE = [&](int s, int buf) {
    const size_t ko = (size_t)s * 64;
    _Float16* ab = As + buf * 4096 + wid * 1024;
    _Float16* bb = Bs + buf * 8192 + wid * 2048;
    gl_lds16(AgL + ko,                     ab);
    gl_lds16(AgL + ko + (size_t) 8 * lda,  ab + 512);
    gl_lds16(BgL + ko,                     bb);
    gl_lds16(BgL + ko + (size_t) 8 * ldb,  bb + 512);
    gl_lds16(BgL + ko + (size_t)16 * ldb,  bb + 1024);
    gl_lds16(BgL + ko + (size_t)24 * ldb,  bb + 1536);
  };

  if (s0 < s1)     STAGE(s0, 0);
  if (s0 + 1 < s1) STAGE(s0 + 1, 1);

  int cur = 0;
  for (int s = s0; s < s1; ++s) {
    __builtin_amdgcn_s_barrier();           // prev step's readers are done
    const bool more2 = (s + 2 < s1), more1 = (s + 1 < s1);
    if (more2) STAGE(s + 2, cur == 0 ? 2 : (cur == 1 ? 0 : 1));
    if (more2)      asm volatile("s_waitcnt vmcnt(12)" ::: "memory");
    else if (more1) asm volatile("s_waitcnt vmcnt(6)"  ::: "memory");
    else            asm volatile("s_waitcnt vmcnt(0)"  ::: "memory");
    __builtin_amdgcn_s_barrier();           // ALL waves' stage(s) complete

    const char* Ab = (const char*)(As + cur * 4096);
    const char* Bb = (const char*)(Bs + cur * 8192);
    half8 af[2][2], bf[4][2];
#pragma unroll
    for (int kc = 0; kc < 2; ++kc) {
#pragma unroll
      for (int mi = 0; mi < 2; ++mi) {
        int row = wr * 32 + mi * 16 + r16;
        af[mi][kc] = *(const half8*)(Ab + row * 128 +
                     (((kc << 6) + (kh << 4)) ^ ((row & 7) << 4)));
      }
#pragma unroll
      for (int ni = 0; ni < 4; ++ni) {
        int row = wc * 64 + ni * 16 + r16;
        bf[ni][kc] = *(const half8*)(Bb + row * 128 +
                     (((kc << 6) + (kh << 4)) ^ ((row & 7) << 4)));
      }
    }
#pragma unroll
    for (int kc = 0; kc < 2; ++kc)
#pragma unroll
      for (int mi = 0; mi < 2; ++mi)
#pragma unroll
        for (int ni = 0; ni < 4; ++ni)
          acc[mi][ni] = __builtin_amdgcn_mfma_f32_16x16x32_f16(
              af[mi][kc], bf[ni][kc], acc[mi][ni], 0, 0, 0);
    cur = cur == 2 ? 0 : cur + 1;
  }

  float* P = part + (size_t)bz * M * Npad;
#pragma unroll
  for (int mi = 0; mi < 2; ++mi)
#pragma unroll
    for (int ni = 0; ni < 4; ++ni) {
      int row = m0 + wr * 32 + mi * 16 + kh * 4;    // C/D: row=(l>>4)*4+rr
      int col = n0 + wc * 64 + ni * 16 + r16;       //      col=l&15
#pragma unroll
      for (int rr = 0; rr < 4; ++rr)
        P[(size_t)(row + rr) * Npad + col] = acc[mi][ni][rr];
    }
}

// ---- combine split-K partials + bias + relu, emit fp16 (vectorized) -------
__global__ void combine_sk(const float* __restrict__ part, int SK, int M, int Npad,
                           const float* __restrict__ bias, int Nreal,
                           _Float16* __restrict__ o16) {
  int i4 = (blockIdx.x * 256 + threadIdx.x) * 4;
  int total = M * Npad;
  if (i4 >= total) return;
  f32x4 s = (f32x4){0.f, 0.f, 0.f, 0.f};
  for (int zz = 0; zz < SK; ++zz)
    s += *(const f32x4*)&part[(size_t)zz * total + i4];
  int n = i4 & (Npad - 1);  // Npad is a power of two, i4 aligned to 4
  half4 v;
#pragma unroll
  for (int e = 0; e < 4; ++e) {
    float x = s[e] + ((n + e) < Nreal ? bias[n + e] : 0.f);
    v[e] = (_Float16)fmaxf(x, 0.f);
  }
  *(half4*)(o16 + i4) = v;
}

// ---- final combine (split-K + bias, no relu) fused with cosine ------------
__global__ void combine_cos(const float* __restrict__ part,
                            const float* __restrict__ bo,
                            float* __restrict__ out) {
  const int b = blockIdx.x, t = threadIdx.x;
  float d = 0.f, s1 = 0.f, s2 = 0.f;
  for (int c = t; c < NOP; c += 256) {
    float e1 = 0.f, e2 = 0.f;
#pragma unroll
    for (int z = 0; z < 8; ++z) {
      e1 += part[((size_t)z * ROWS + b) * NOP + c];
      e2 += part[((size_t)z * ROWS + b + BATCH) * NOP + c];
    }
    if (c < 500) { float bb = bo[c]; e1 += bb; e2 += bb; }
    d += e1 * e2; s1 += e1 * e1; s2 += e2 * e2;
  }
  for (int off = 32; off > 0; off >>= 1) {
    d  += __shfl_down(d, off, 64);
    s1 += __shfl_down(s1, off, 64);
    s2 += __shfl_down(s2, off, 64);
  }
  __shared__ float rd[4], r1[4], r2[4];
  int wd = t >> 6, lane = t & 63;
  if (lane == 0) { rd[wd] = d; r1[wd] = s1; r2[wd] = s2; }
  __syncthreads();
  if (t == 0) {
    float D  = rd[0] + rd[1] + rd[2] + rd[3];
    float S1 = r1[0] + r1[1] + r1[2] + r1[3];
    float S2 = r2[0] + r2[1] + r2[2] + r2[3];
    float n1 = fmaxf(sqrtf(S1), 1e-6f);
    float n2 = fmaxf(sqrtf(S2), 1e-6f);
    out[b] = D / (n1 * n2);
  }
}

extern "C" void kernel_launch(void* const* d_in, const int* in_sizes, int n_in,
                              void* d_out, int out_size, void* d_ws, size_t ws_size,
                              hipStream_t stream) {
  const float* mz1 = (const float*)d_in[0];
  const float* it1 = (const float*)d_in[1];
  const float* mz2 = (const float*)d_in[2];
  const float* it2 = (const float*)d_in[3];
  const float* Wg  = (const float*)d_in[4];
  const float* bg  = (const float*)d_in[5];
  const float* W1  = (const float*)d_in[6];
  const float* b1  = (const float*)d_in[7];
  const float* W2  = (const float*)d_in[8];
  const float* b2  = (const float*)d_in[9];
  const float* W3  = (const float*)d_in[10];
  const float* b3  = (const float*)d_in[11];
  const float* Wo  = (const float*)d_in[12];
  const float* bo  = (const float*)d_in[13];
  float* out = (float*)d_out;

  char* ws = (char*)d_ws;
  size_t off = 0;
  auto take = [&](size_t bytes) {
    size_t o = off; off += (bytes + 255) & ~(size_t)255; return o;
  };
  float*    part = (float*)   (ws + take((size_t)8 * ROWS * NP * 4));  // 16MB
  _Float16* h16  = (_Float16*)(ws + take((size_t)ROWS * K1P * 2));
  _Float16* W1t  = (_Float16*)(ws + take((size_t)NP * K1P * 2));
  _Float16* W2t  = (_Float16*)(ws + take((size_t)NP * NP * 2));
  _Float16* W3t  = (_Float16*)(ws + take((size_t)NP * NP * 2));
  _Float16* Wot  = (_Float16*)(ws + take((size_t)NOP * NP * 2));
  _Float16* y1   = (_Float16*)(ws + take((size_t)ROWS * NP * 2));
  _Float16* y2   = (_Float16*)(ws + take((size_t)ROWS * NP * 2));
  _Float16* y3   = (_Float16*)(ws + take((size_t)ROWS * NP * 2));

  // 1) binning + grouped linear + all weight transposes, ONE dispatch
  prep3<<<1824, 256, 0, stream>>>(mz1, it1, mz2, it2, Wg, bg, h16,
                                  W1, W1t, W2, W2t, W3, W3t, Wo, Wot);

  // 2) MLP. L1: 157 K-steps of 64, SK=8 (kspc 20); L2/L3/Lo: 16 steps, SK=8.
  gemm_sk<true><<<512, 256, 0, stream>>>(
      h16, K1P, W1t, K1P, part, ROWS, NP, K1P / 64, 20);
  combine_sk<<<(ROWS * NP) / 1024, 256, 0, stream>>>(part, 8, ROWS, NP, b1, 1000, y1);

  gemm_sk<true><<<512, 256, 0, stream>>>(
      y1, NP, W2t, NP, part, ROWS, NP, NP / 64, 2);
  combine_sk<<<(ROWS * NP) / 1024, 256, 0, stream>>>(part, 8, ROWS, NP, b2, 1000, y2);

  gemm_sk<true><<<512, 256, 0, stream>>>(
      y2, NP, W3t, NP, part, ROWS, NP, NP / 64, 2);
  combine_sk<<<(ROWS * NP) / 1024, 256, 0, stream>>>(part, 8, ROWS, NP, b3, 1000, y3);

  gemm_sk<false><<<dim3(NOP / 128, ROWS / 64, 8), 256, 0, stream>>>(
      y3, NP, Wot, NP, part, ROWS, NOP, NP / 64, 2);

  // 3) final combine + cosine
  combine_cos<<<BATCH, 256, 0, stream>>>(part, bo, out);
}

// Round 9
// 97.516 us; speedup vs baseline: 1.1832x; 1.0075x over previous
//
#include <hip/hip_runtime.h>
#include <hip/hip_fp16.h>

using half8  = __attribute__((ext_vector_type(8))) _Float16;
using half4  = __attribute__((ext_vector_type(4))) _Float16;
using f32x4  = __attribute__((ext_vector_type(4))) float;

#define GROUPS      3333
#define BINNER_OUT  9999
#define BATCH       256
#define ROWS        512          // 2 spectra x 256
#define PEAKS       512
#define K1          9999
#define K1P         10048        // padded to mult of 64 (157*64)
#define NP          1024         // hidden 1000 padded
#define NOP         512          // out 500 padded
#define HALFK       5024         // K1P/2, per-bin-block column range

// ---- async global->LDS, 16B per lane (dest = uniform base + lane*16) ------
__device__ __forceinline__ void gl_lds16(const void* g, void* l) {
  __builtin_amdgcn_global_load_lds(
      (const __attribute__((address_space(1))) void*)g,
      (__attribute__((address_space(3))) void*)l, 16, 0, 0);
}

// ---- native LDS fp32 atomic add (relaxed, workgroup scope -> ds_add_f32) --
__device__ __forceinline__ void hs_add(float* p, float v) {
  __hip_atomic_fetch_add(p, v, __ATOMIC_RELAXED, __HIP_MEMORY_SCOPE_WORKGROUP);
}

// ---- prep4: binning (1024 blocks, half-row each) + transposes (800) -------
// Uniform 20.1 KB LDS -> 8 blocks/CU for both paths.
// bin path [0,1024): native ds_add_f32 atomics; all peak + Wg gather loads
//   issued before the atomic phase (max ILP, no guarded dependent chain).
// transp   [1024,1824): 4 x (64x64) tiles/block, T14 register staging.
__global__ __launch_bounds__(256) void prep4(
    const float* __restrict__ mz1, const float* __restrict__ it1,
    const float* __restrict__ mz2, const float* __restrict__ it2,
    const float* __restrict__ Wg,  const float* __restrict__ bg,
    _Float16* __restrict__ h16,
    const float* __restrict__ W1, _Float16* __restrict__ W1t,
    const float* __restrict__ W2, _Float16* __restrict__ W2t,
    const float* __restrict__ W3, _Float16* __restrict__ W3t,
    const float* __restrict__ Wo, _Float16* __restrict__ Wot) {
  __shared__ __align__(16) char smem[HALFK * 4];    // 20096 B
  const int t = threadIdx.x;
  const int blk = blockIdx.x;

  if (blk < 1024) {
    // ---------------- binning + grouped linear (half row) ----------------
    float* hs = (float*)smem;                       // 5024 floats
    const int row = blk >> 1, half = blk & 1;
    const int base = half * HALFK;
    const int s = row >> 8, b = row & 255;

    for (int k = t * 4; k < HALFK; k += 1024)
      *(f32x4*)&hs[k] = (f32x4){0.f, 0.f, 0.f, 0.f};
    __syncthreads();

    const float* mz = (s ? mz2 : mz1) + (size_t)b * PEAKS;
    const float* it = (s ? it2 : it1) + (size_t)b * PEAKS;

    // phase 1: issue ALL loads (peaks + unconditional clamped Wg gathers)
    float m[2], v[2], w[2][3]; int c0[2]; bool keep[2];
#pragma unroll
    for (int q = 0; q < 2; ++q) { m[q] = mz[t + q * 256]; v[q] = it[t + q * 256]; }
#pragma unroll
    for (int q = 0; q < 2; ++q) {
      bool val = (m[q] >= 0.0f && m[q] < 1000.0f);
      int bin = val ? (int)floorf(m[q] / 0.01f) : 0;  // IEEE div+floor = jnp
      bin = bin < 0 ? 0 : (bin > 99999 ? 99999 : bin);
      keep[q] = val && (bin < GROUPS * 30);       // ref drops bins 99990..99999
      int binL = bin < GROUPS * 30 ? bin : GROUPS * 30 - 1;  // safe gather idx
      const float* wp = Wg + (size_t)binL * 3;    // Wg[g][i][o] flat
      w[q][0] = wp[0]; w[q][1] = wp[1]; w[q][2] = wp[2];
      c0[q] = (bin / 30) * 3;
    }
    // phase 2: predicated native atomics
#pragma unroll
    for (int q = 0; q < 2; ++q)
      if (keep[q]) {
#pragma unroll
        for (int o = 0; o < 3; ++o) {
          int c = c0[q] + o;
          if (c >= base && c < base + HALFK)
            hs_add(&hs[c - base], v[q] * w[q][o]);
        }
      }
    __syncthreads();

    _Float16* dst = h16 + (size_t)row * K1P + base;
    for (int k0 = t * 8; k0 < HALFK; k0 += 2048) {
      half8 vv;
#pragma unroll
      for (int j = 0; j < 8; ++j) {
        int c = base + k0 + j;
        float x = hs[k0 + j] + (c < BINNER_OUT ? bg[c] : 0.f);
        vv[j] = (_Float16)x;
      }
      *(half8*)(dst + k0) = vv;
    }
  } else {
    // ------- weight transpose+convert, 4 x (64x64) tiles per block -------
    // out[n*Kpad + k] = fp16(W[k*N + n]), zero-padded.
    float (*tile)[66] = (float(*)[66])smem;         // 16896 B
    int bid = blk - 1024;
    const float* W; _Float16* outp; int K, N, Kpad, g, in, ktiles;
    if (bid < 640)       { W = W1; outp = W1t; K = K1;   N = 1000; Kpad = K1P;
                           ktiles = 157; g = bid % 40; in = bid / 40; }
    else if (bid < 704)  { bid -= 640; W = W2; outp = W2t; K = 1000; N = 1000;
                           Kpad = NP; ktiles = 16; g = bid & 3; in = bid >> 2; }
    else if (bid < 768)  { bid -= 704; W = W3; outp = W3t; K = 1000; N = 1000;
                           Kpad = NP; ktiles = 16; g = bid & 3; in = bid >> 2; }
    else                 { bid -= 768; W = Wo; outp = Wot; K = 1000; N = 500;
                           Kpad = NP; ktiles = 16; g = bid & 3; in = bid >> 2; }
    const int ntile = min(4, ktiles - g * 4);
    const int k0base = g * 256, n0 = in * 64;
    const int r = t >> 2, cc = (t & 3) * 16;

    f32x4 cur[4], nxt[4];
    auto LOAD = [&](int i, f32x4* dst) {            // tile i of this group
      int k = k0base + i * 64 + r;
#pragma unroll
      for (int j = 0; j < 4; ++j) {
        int n = n0 + cc + j * 4;
        f32x4 v = (f32x4){0.f, 0.f, 0.f, 0.f};
        if (k < K && n < N)                 // N % 4 == 0: whole-chunk validity
          v = *(const f32x4*)(W + (size_t)k * N + n);
        dst[j] = v;
      }
    };

    LOAD(0, cur);
    for (int i = 0; i < ntile; ++i) {
      if (i) __syncthreads();               // prior tile's col-reads done
#pragma unroll
      for (int j = 0; j < 4; ++j) {
        tile[r][cc + j * 4 + 0] = cur[j][0];
        tile[r][cc + j * 4 + 1] = cur[j][1];
        tile[r][cc + j * 4 + 2] = cur[j][2];
        tile[r][cc + j * 4 + 3] = cur[j][3];
      }
      __syncthreads();
      if (i + 1 < ntile) LOAD(i + 1, nxt);  // in flight across store phase
      const int k0 = k0base + i * 64;
#pragma unroll
      for (int h = 0; h < 2; ++h) {
        half8 v;
#pragma unroll
        for (int e = 0; e < 8; ++e) v[e] = (_Float16)tile[cc + h * 8 + e][r];
        *(half8*)(outp + (size_t)(n0 + r) * Kpad + k0 + cc + h * 8) = v;
      }
#pragma unroll
      for (int j = 0; j < 4; ++j) cur[j] = nxt[j];
    }
  }
}

// ---- split-K fp16 MFMA GEMM, 3-deep counted-vmcnt pipeline ----------------
template <bool SWZ>
__global__ __launch_bounds__(256) void gemm_sk(
    const _Float16* __restrict__ A, int lda,
    const _Float16* __restrict__ Bt, int ldb,
    float* __restrict__ part, int M, int Npad, int ksteps_total, int kspc) {
  __shared__ __align__(16) _Float16 As[3 * 4096];   // 3 x 64x64  = 24 KB
  __shared__ __align__(16) _Float16 Bs[3 * 8192];   // 3 x 128x64 = 48 KB

  int bx, by, bz;
  if (SWZ) {   // 512 blocks = 8x8x8; each XCD owns a 2(bx) x 4(by) region
    int bid = blockIdx.x;
    int xcd = bid & 7, i = bid >> 3;
    bz = i >> 3;
    int j = i & 7;
    bx = (xcd & 3) * 2 + (j & 1);
    by = (xcd >> 2) * 4 + (j >> 1);
  } else {
    bx = blockIdx.x; by = blockIdx.y; bz = blockIdx.z;
  }

  const int t = threadIdx.x, lane = t & 63, wid = t >> 6;
  const int m0 = by * 64, n0 = bx * 128;
  const int s0 = bz * kspc;
  const int s1 = min(s0 + kspc, ksteps_total);

  const int wr = wid >> 1, wc = wid & 1;            // 2x2 waves, 32x64 each
  const int r16 = lane & 15, kh = lane >> 4;

  const int lr  = lane >> 3;
  const int lkc = ((lane & 7) ^ lr) * 8;
  const _Float16* AgL = A  + (size_t)(m0 + wid * 16 + lr) * lda + lkc;
  const _Float16* BgL = Bt + (size_t)(n0 + wid * 32 + lr) * ldb + lkc;

  f32x4 acc[2][4] = {};

  auto STAGE = [&](int s, int buf) {
    const size_t ko = (size_t)s * 64;
    _Float16* ab = As + buf * 4096 + wid * 1024;
    _Float16* bb = Bs + buf * 8192 + wid * 2048;
    gl_lds16(AgL + ko,                     ab);
    gl_lds16(AgL + ko + (size_t) 8 * lda,  ab + 512);
    gl_lds16(BgL + ko,                     bb);
    gl_lds16(BgL + ko + (size_t) 8 * ldb,  bb + 512);
    gl_lds16(BgL + ko + (size_t)16 * ldb,  bb + 1024);
    gl_lds16(BgL + ko + (size_t)24 * ldb,  bb + 1536);
  };

  if (s0 < s1)     STAGE(s0, 0);
  if (s0 + 1 < s1) STAGE(s0 + 1, 1);

  int cur = 0;
  for (int s = s0; s < s1; ++s) {
    __builtin_amdgcn_s_barrier();           // prev step's readers are done
    const bool more2 = (s + 2 < s1), more1 = (s + 1 < s1);
    if (more2) STAGE(s + 2, cur == 0 ? 2 : (cur == 1 ? 0 : 1));
    if (more2)      asm volatile("s_waitcnt vmcnt(12)" ::: "memory");
    else if (more1) asm volatile("s_waitcnt vmcnt(6)"  ::: "memory");
    else            asm volatile("s_waitcnt vmcnt(0)"  ::: "memory");
    __builtin_amdgcn_s_barrier();           // ALL waves' stage(s) complete

    const char* Ab = (const char*)(As + cur * 4096);
    const char* Bb = (const char*)(Bs + cur * 8192);
    half8 af[2][2], bf[4][2];
#pragma unroll
    for (int kc = 0; kc < 2; ++kc) {
#pragma unroll
      for (int mi = 0; mi < 2; ++mi) {
        int row = wr * 32 + mi * 16 + r16;
        af[mi][kc] = *(const half8*)(Ab + row * 128 +
                     (((kc << 6) + (kh << 4)) ^ ((row & 7) << 4)));
      }
#pragma unroll
      for (int ni = 0; ni < 4; ++ni) {
        int row = wc * 64 + ni * 16 + r16;
        bf[ni][kc] = *(const half8*)(Bb + row * 128 +
                     (((kc << 6) + (kh << 4)) ^ ((row & 7) << 4)));
      }
    }
#pragma unroll
    for (int kc = 0; kc < 2; ++kc)
#pragma unroll
      for (int mi = 0; mi < 2; ++mi)
#pragma unroll
        for (int ni = 0; ni < 4; ++ni)
          acc[mi][ni] = __builtin_amdgcn_mfma_f32_16x16x32_f16(
              af[mi][kc], bf[ni][kc], acc[mi][ni], 0, 0, 0);
    cur = cur == 2 ? 0 : cur + 1;
  }

  float* P = part + (size_t)bz * M * Npad;
#pragma unroll
  for (int mi = 0; mi < 2; ++mi)
#pragma unroll
    for (int ni = 0; ni < 4; ++ni) {
      int row = m0 + wr * 32 + mi * 16 + kh * 4;    // C/D: row=(l>>4)*4+rr
      int col = n0 + wc * 64 + ni * 16 + r16;       //      col=l&15
#pragma unroll
      for (int rr = 0; rr < 4; ++rr)
        P[(size_t)(row + rr) * Npad + col] = acc[mi][ni][rr];
    }
}

// ---- combine split-K partials + bias + relu, emit fp16 (vectorized) -------
__global__ void combine_sk(const float* __restrict__ part, int SK, int M, int Npad,
                           const float* __restrict__ bias, int Nreal,
                           _Float16* __restrict__ o16) {
  int i4 = (blockIdx.x * 256 + threadIdx.x) * 4;
  int total = M * Npad;
  if (i4 >= total) return;
  f32x4 s = (f32x4){0.f, 0.f, 0.f, 0.f};
  for (int zz = 0; zz < SK; ++zz)
    s += *(const f32x4*)&part[(size_t)zz * total + i4];
  int n = i4 & (Npad - 1);  // Npad is a power of two, i4 aligned to 4
  half4 v;
#pragma unroll
  for (int e = 0; e < 4; ++e) {
    float x = s[e] + ((n + e) < Nreal ? bias[n + e] : 0.f);
    v[e] = (_Float16)fmaxf(x, 0.f);
  }
  *(half4*)(o16 + i4) = v;
}

// ---- final combine (split-K + bias, no relu) fused with cosine ------------
__global__ void combine_cos(const float* __restrict__ part,
                            const float* __restrict__ bo,
                            float* __restrict__ out) {
  const int b = blockIdx.x, t = threadIdx.x;
  float d = 0.f, s1 = 0.f, s2 = 0.f;
  for (int c = t; c < NOP; c += 256) {
    float e1 = 0.f, e2 = 0.f;
#pragma unroll
    for (int z = 0; z < 8; ++z) {
      e1 += part[((size_t)z * ROWS + b) * NOP + c];
      e2 += part[((size_t)z * ROWS + b + BATCH) * NOP + c];
    }
    if (c < 500) { float bb = bo[c]; e1 += bb; e2 += bb; }
    d += e1 * e2; s1 += e1 * e1; s2 += e2 * e2;
  }
  for (int off = 32; off > 0; off >>= 1) {
    d  += __shfl_down(d, off, 64);
    s1 += __shfl_down(s1, off, 64);
    s2 += __shfl_down(s2, off, 64);
  }
  __shared__ float rd[4], r1[4], r2[4];
  int wd = t >> 6, lane = t & 63;
  if (lane == 0) { rd[wd] = d; r1[wd] = s1; r2[wd] = s2; }
  __syncthreads();
  if (t == 0) {
    float D  = rd[0] + rd[1] + rd[2] + rd[3];
    float S1 = r1[0] + r1[1] + r1[2] + r1[3];
    float S2 = r2[0] + r2[1] + r2[2] + r2[3];
    float n1 = fmaxf(sqrtf(S1), 1e-6f);
    float n2 = fmaxf(sqrtf(S2), 1e-6f);
    out[b] = D / (n1 * n2);
  }
}

extern "C" void kernel_launch(void* const* d_in, const int* in_sizes, int n_in,
                              void* d_out, int out_size, void* d_ws, size_t ws_size,
                              hipStream_t stream) {
  const float* mz1 = (const float*)d_in[0];
  const float* it1 = (const float*)d_in[1];
  const float* mz2 = (const float*)d_in[2];
  const float* it2 = (const float*)d_in[3];
  const float* Wg  = (const float*)d_in[4];
  const float* bg  = (const float*)d_in[5];
  const float* W1  = (const float*)d_in[6];
  const float* b1  = (const float*)d_in[7];
  const float* W2  = (const float*)d_in[8];
  const float* b2  = (const float*)d_in[9];
  const float* W3  = (const float*)d_in[10];
  const float* b3  = (const float*)d_in[11];
  const float* Wo  = (const float*)d_in[12];
  const float* bo  = (const float*)d_in[13];
  float* out = (float*)d_out;

  char* ws = (char*)d_ws;
  size_t off = 0;
  auto take = [&](size_t bytes) {
    size_t o = off; off += (bytes + 255) & ~(size_t)255; return o;
  };
  float*    part = (float*)   (ws + take((size_t)8 * ROWS * NP * 4));  // 16MB
  _Float16* h16  = (_Float16*)(ws + take((size_t)ROWS * K1P * 2));
  _Float16* W1t  = (_Float16*)(ws + take((size_t)NP * K1P * 2));
  _Float16* W2t  = (_Float16*)(ws + take((size_t)NP * NP * 2));
  _Float16* W3t  = (_Float16*)(ws + take((size_t)NP * NP * 2));
  _Float16* Wot  = (_Float16*)(ws + take((size_t)NOP * NP * 2));
  _Float16* y1   = (_Float16*)(ws + take((size_t)ROWS * NP * 2));
  _Float16* y2   = (_Float16*)(ws + take((size_t)ROWS * NP * 2));
  _Float16* y3   = (_Float16*)(ws + take((size_t)ROWS * NP * 2));

  // 1) binning + grouped linear + all weight transposes, ONE dispatch
  prep4<<<1824, 256, 0, stream>>>(mz1, it1, mz2, it2, Wg, bg, h16,
                                  W1, W1t, W2, W2t, W3, W3t, Wo, Wot);

  // 2) MLP. L1: 157 K-steps of 64, SK=8 (kspc 20); L2/L3/Lo: 16 steps, SK=8.
  gemm_sk<true><<<512, 256, 0, stream>>>(
      h16, K1P, W1t, K1P, part, ROWS, NP, K1P / 64, 20);
  combine_sk<<<(ROWS * NP) / 1024, 256, 0, stream>>>(part, 8, ROWS, NP, b1, 1000, y1);

  gemm_sk<true><<<512, 256, 0, stream>>>(
      y1, NP, W2t, NP, part, ROWS, NP, NP / 64, 2);
  combine_sk<<<(ROWS * NP) / 1024, 256, 0, stream>>>(part, 8, ROWS, NP, b2, 1000, y2);

  gemm_sk<true><<<512, 256, 0, stream>>>(
      y2, NP, W3t, NP, part, ROWS, NP, NP / 64, 2);
  combine_sk<<<(ROWS * NP) / 1024, 256, 0, stream>>>(part, 8, ROWS, NP, b3, 1000, y3);

  gemm_sk<false><<<dim3(NOP / 128, ROWS / 64, 8), 256, 0, stream>>>(
      y3, NP, Wot, NP, part, ROWS, NOP, NP / 64, 2);

  // 3) final combine + cosine
  combine_cos<<<BATCH, 256, 0, stream>>>(part, bo, out);
}